// Round 5
// baseline (496.898 us; speedup 1.0000x reference)
//
#include <hip/hip_runtime.h>
#include <hip/hip_bf16.h>

#define BATCH 4096
#define NTOT  8192
#define DIM   512

typedef __attribute__((ext_vector_type(8))) __bf16 bf16x8;
typedef __attribute__((ext_vector_type(4))) float  floatx4;

__device__ __forceinline__ unsigned short f2bf(float x) {
  union { float f; unsigned u; } v; v.f = x;
  unsigned r = v.u + 0x7fffu + ((v.u >> 16) & 1u);   // RNE
  return (unsigned short)(r >> 16);
}

// ---------------------------------------------------------------- normalize
// One wave per row: read 512 fp32, rsqrt(sum sq), write 512 bf16.
// Blocks 0..31 also zero S; block 0 zeroes the done-counter.
__global__ __launch_bounds__(256) void nrm_kernel(const float* __restrict__ zi,
                                                  const float* __restrict__ zj,
                                                  ushort* __restrict__ zn,
                                                  float* __restrict__ S,
                                                  unsigned* __restrict__ done) {
  if (blockIdx.x < 32) S[blockIdx.x * 256 + threadIdx.x] = 0.0f;
  if (blockIdx.x == 0 && threadIdx.x == 0) *done = 0u;
  const int row = blockIdx.x * 4 + (threadIdx.x >> 6);
  const int l   = threadIdx.x & 63;
  const float* src = (row < BATCH) ? (zi + (size_t)row * DIM)
                                   : (zj + (size_t)(row - BATCH) * DIM);
  const float4* s4 = (const float4*)src;
  float4 v0 = s4[l];
  float4 v1 = s4[l + 64];
  float ss = v0.x*v0.x + v0.y*v0.y + v0.z*v0.z + v0.w*v0.w
           + v1.x*v1.x + v1.y*v1.y + v1.z*v1.z + v1.w*v1.w;
  #pragma unroll
  for (int m = 1; m < 64; m <<= 1) ss += __shfl_xor(ss, m, 64);
  const float r = 1.0f / fmaxf(sqrtf(ss), 1e-12f);
  ushort4 o0, o1;
  o0.x = f2bf(v0.x * r); o0.y = f2bf(v0.y * r);
  o0.z = f2bf(v0.z * r); o0.w = f2bf(v0.w * r);
  o1.x = f2bf(v1.x * r); o1.y = f2bf(v1.y * r);
  o1.z = f2bf(v1.z * r); o1.w = f2bf(v1.w * r);
  ushort4* d4 = (ushort4*)(zn + (size_t)row * DIM);
  d4[l]      = o0;
  d4[l + 64] = o1;
}

// ---------------------------------------------------------------- main GEMM
// 2D grid (bi = x fastest, bj = y), early-exit lower triangle: consecutive
// blocks share bj -> B band L1/L2-resident (R2 measured FETCH 31 MB).
// NO LDS staging, NO barriers in the K-loop: since both operands are rows of
// zn, each wave gathers its MFMA fragments directly from global (16 rows x
// 16 B = 16 full cache lines per load). Compiler is free to software-pipeline
// with fine-grained vmcnt(N) — the restructured K-loop the m97 plateau needs.
// Loss fused via last-block done-counter (device-scope atomics + fences).
__global__ __launch_bounds__(256, 4) void simsum_kernel(const ushort* __restrict__ zn,
                                                        float* __restrict__ S,
                                                        float* __restrict__ P,
                                                        unsigned* __restrict__ done,
                                                        float* __restrict__ out) {
  const int bi = blockIdx.x;
  const int bj = blockIdx.y;
  const int t  = threadIdx.x;
  const int w  = t >> 6;
  const int l  = t & 63;

  if (bj >= bi) {
    const bool diag = (bi == bj);
    const bool posb = (bj == bi + BATCH / 128);
    const int tileRow = bi * 128;
    const int tileCol = bj * 128;

    const int quad = l >> 4;
    const int lo   = l & 15;
    const int wm   = w >> 1;
    const int wn   = w & 1;

    __shared__ float redR[2][128];
    __shared__ float redC[2][128];

    // fragment bases: lane lo reads row (tile + w*64 + frag*16 + lo),
    // k-chunk quad (16 B). Frag stride = 16 rows = 16*DIM elements.
    const ushort* aB = zn + (size_t)(tileRow + wm * 64 + lo) * DIM + quad * 8;
    const ushort* bB = zn + (size_t)(tileCol + wn * 64 + lo) * DIM + quad * 8;

    floatx4 acc[4][4];
    #pragma unroll
    for (int i = 0; i < 4; ++i)
      #pragma unroll
      for (int j = 0; j < 4; ++j)
        acc[i][j] = (floatx4){0.f, 0.f, 0.f, 0.f};

    #pragma unroll 2
    for (int kb = 0; kb < DIM; kb += 32) {
      bf16x8 aF[4], bF[4];
      #pragma unroll
      for (int i = 0; i < 4; ++i)
        aF[i] = *(const bf16x8*)(aB + (size_t)i * 16 * DIM + kb);
      #pragma unroll
      for (int j = 0; j < 4; ++j)
        bF[j] = *(const bf16x8*)(bB + (size_t)j * 16 * DIM + kb);
      #pragma unroll
      for (int i = 0; i < 4; ++i)
        #pragma unroll
        for (int j = 0; j < 4; ++j)
          acc[i][j] = __builtin_amdgcn_mfma_f32_16x16x32_bf16(aF[i], bF[j],
                                                              acc[i][j], 0, 0, 0);
    }

    // ---- epilogue. C/D layout: col = lo, row = quad*4 + r (within 16x16)
    float rs[4][4];
    float cs[4];
    #pragma unroll
    for (int i = 0; i < 4; ++i)
      #pragma unroll
      for (int r = 0; r < 4; ++r) rs[i][r] = 0.f;
    #pragma unroll
    for (int j = 0; j < 4; ++j) cs[j] = 0.f;

    #pragma unroll
    for (int i = 0; i < 4; ++i)
      #pragma unroll
      for (int j = 0; j < 4; ++j)
        #pragma unroll
        for (int r = 0; r < 4; ++r) {
          const float e = __expf(acc[i][j][r] * 10.0f - 10.0f);
          rs[i][r] += e;
          cs[j] += e;
        }

    // block-local diagonal lanes: wm==wn, lo == quad*4 + r (quad == lo>>2)
    if (wm == wn && quad == (lo >> 2)) {
      const int r = lo & 3;
      if (diag) {  // remove self-similarity from row & col sums
        #pragma unroll
        for (int i = 0; i < 4; ++i) {
          const float e = __expf(acc[i][i][r] * 10.0f - 10.0f);
          rs[i][r] -= e;
          cs[i] -= e;
        }
      }
      if (posb) {  // positives: col == row + BATCH
        #pragma unroll
        for (int i = 0; i < 4; ++i) {
          const int row = tileRow + wm * 64 + i * 16 + lo;
          const float v = acc[i][i][r] * 10.0f;
          P[row] = v;
          P[row + BATCH] = v;
        }
      }
    }

    // row sums: reduce across 16 column-lanes (low 4 lane bits)
    #pragma unroll
    for (int m = 1; m < 16; m <<= 1) {
      #pragma unroll
      for (int i = 0; i < 4; ++i)
        #pragma unroll
        for (int r = 0; r < 4; ++r)
          rs[i][r] += __shfl_xor(rs[i][r], m, 64);
    }
    if (lo == 0) {
      #pragma unroll
      for (int i = 0; i < 4; ++i)
        #pragma unroll
        for (int r = 0; r < 4; ++r)
          redR[wn][wm * 64 + i * 16 + quad * 4 + r] = rs[i][r];
    }
    // col sums: reduce across the 4 quads (lane bits 4,5)
    #pragma unroll
    for (int m = 16; m < 64; m <<= 1) {
      #pragma unroll
      for (int j = 0; j < 4; ++j) cs[j] += __shfl_xor(cs[j], m, 64);
    }
    if (quad == 0) {
      #pragma unroll
      for (int j = 0; j < 4; ++j)
        redC[wm][wn * 64 + j * 16 + lo] = cs[j];
    }
    __syncthreads();
    if (t < 128) {
      atomicAdd(&S[tileRow + t], redR[0][t] + redR[1][t]);
    } else if (!diag) {
      const int c = t - 128;
      atomicAdd(&S[tileCol + c], redC[0][c] + redC[1][c]);
    }
  }

  // ---- last-block loss reduction (all 4096 blocks pass through here)
  __threadfence();                       // release S/P updates (device scope)
  __shared__ unsigned ticket;
  if (t == 0) ticket = atomicAdd(done, 1u);
  __syncthreads();
  if (ticket == 64 * 64 - 1) {
    __threadfence();                     // acquire all other blocks' S/P
    float acc = 0.f;
    for (int i = t; i < NTOT; i += 256)
      acc += 10.0f + logf(S[i]) - P[i];
    #pragma unroll
    for (int m = 1; m < 64; m <<= 1) acc += __shfl_xor(acc, m, 64);
    __shared__ float sb[4];
    if (l == 0) sb[w] = acc;
    __syncthreads();
    if (t == 0)
      out[0] = (sb[0] + sb[1] + sb[2] + sb[3]) * (1.0f / (float)NTOT);
  }
}

extern "C" void kernel_launch(void* const* d_in, const int* in_sizes, int n_in,
                              void* d_out, int out_size, void* d_ws, size_t ws_size,
                              hipStream_t stream) {
  const float* zi = (const float*)d_in[0];
  const float* zj = (const float*)d_in[1];
  ushort*   zn   = (ushort*)d_ws;                                  // 8 MB bf16
  float*    S    = (float*)((char*)d_ws + (size_t)NTOT * DIM * 2); // 32 KB
  float*    P    = S + NTOT;                                       // 32 KB
  unsigned* done = (unsigned*)(P + NTOT);                          // 4 B
  float*    out  = (float*)d_out;

  nrm_kernel<<<NTOT / 4, 256, 0, stream>>>(zi, zj, zn, S, done);
  simsum_kernel<<<dim3(64, 64), 256, 0, stream>>>(zn, S, P, done, out);
}

// Round 6
// 251.919 us; speedup vs baseline: 1.9725x; 1.9725x over previous
//
#include <hip/hip_runtime.h>
#include <hip/hip_bf16.h>

#define BATCH 4096
#define NTOT  8192
#define DIM   512
#define NTILE 2080   // 64*65/2 upper-triangular 128x128 tiles

typedef __attribute__((ext_vector_type(8))) __bf16 bf16x8;
typedef __attribute__((ext_vector_type(4))) float  floatx4;

__device__ __forceinline__ unsigned short f2bf(float x) {
  union { float f; unsigned u; } v; v.f = x;
  unsigned r = v.u + 0x7fffu + ((v.u >> 16) & 1u);   // RNE
  return (unsigned short)(r >> 16);
}

#define ASYNC16(gp, lp)                                                        \
  __builtin_amdgcn_global_load_lds(                                            \
      (__attribute__((address_space(1))) void*)(gp),                           \
      (__attribute__((address_space(3))) void*)(lp), 16, 0, 0)

// raw barrier + fine-grained vmcnt: keep prefetch loads in flight across the
// barrier (the m97-plateau fix; compiler's __syncthreads would drain vmcnt(0))
#define SWAIT4() asm volatile("s_waitcnt vmcnt(4)" ::: "memory")
#define SWAIT0() asm volatile("s_waitcnt vmcnt(0)" ::: "memory")
#define SBAR()   asm volatile("s_barrier" ::: "memory")

// ---------------------------------------------------------------- normalize
// One wave per row: read 512 fp32, rsqrt(sum sq), write 512 bf16.
// Blocks 0..31 also zero S; block 0 zeroes the done-counter.
__global__ __launch_bounds__(256) void nrm_kernel(const float* __restrict__ zi,
                                                  const float* __restrict__ zj,
                                                  ushort* __restrict__ zn,
                                                  float* __restrict__ S,
                                                  unsigned* __restrict__ done) {
  if (blockIdx.x < 32) S[blockIdx.x * 256 + threadIdx.x] = 0.0f;
  if (blockIdx.x == 0 && threadIdx.x == 0) *done = 0u;
  const int row = blockIdx.x * 4 + (threadIdx.x >> 6);
  const int l   = threadIdx.x & 63;
  const float* src = (row < BATCH) ? (zi + (size_t)row * DIM)
                                   : (zj + (size_t)(row - BATCH) * DIM);
  const float4* s4 = (const float4*)src;
  float4 v0 = s4[l];
  float4 v1 = s4[l + 64];
  float ss = v0.x*v0.x + v0.y*v0.y + v0.z*v0.z + v0.w*v0.w
           + v1.x*v1.x + v1.y*v1.y + v1.z*v1.z + v1.w*v1.w;
  #pragma unroll
  for (int m = 1; m < 64; m <<= 1) ss += __shfl_xor(ss, m, 64);
  const float r = 1.0f / fmaxf(sqrtf(ss), 1e-12f);
  ushort4 o0, o1;
  o0.x = f2bf(v0.x * r); o0.y = f2bf(v0.y * r);
  o0.z = f2bf(v0.z * r); o0.w = f2bf(v0.w * r);
  o1.x = f2bf(v1.x * r); o1.y = f2bf(v1.y * r);
  o1.z = f2bf(v1.z * r); o1.w = f2bf(v1.w * r);
  ushort4* d4 = (ushort4*)(zn + (size_t)row * DIM);
  d4[l]      = o0;
  d4[l + 64] = o1;
}

// ---------------------------------------------------------------- main GEMM
// Compact triangular grid (2080 blocks), XCD-swizzled so each XCD's tiles
// share contiguous bj bands in its private L2. 3-stage LDS ring with raw
// s_barrier + manual vmcnt(4): stage-(it+2) loads issued at iter it stay in
// flight across TWO compute phases (~1400 cyc > 900-cyc HBM miss latency).
// Ring-safety: buf (it+2)%3 was last ds_read in iter it-1; those reads
// complete (lgkm before MFMA use) before any wave reaches barrier(it).
// XOR bank swizzle on k-chunks: 0 LDS conflicts (verified R2/R3).
// Loss fused via last-block ticket (device-scope atomics + fences).
__global__ __launch_bounds__(256, 3) void simsum_kernel(const ushort* __restrict__ zn,
                                                        float* __restrict__ S,
                                                        float* __restrict__ P,
                                                        unsigned* __restrict__ done,
                                                        float* __restrict__ out) {
  // XCD swizzle (XCD ~ blockIdx%8): XCD k owns contiguous tiles [260k,260k+260)
  const int b = blockIdx.x;
  const int u = (b & 7) * 260 + (b >> 3);
  // triangle decode: u = bj*(bj+1)/2 + bi, bi <= bj < 64
  int bj = (int)((sqrtf(8.0f * (float)u + 1.0f) - 1.0f) * 0.5f);
  while ((bj + 1) * (bj + 2) / 2 <= u) ++bj;
  while (bj * (bj + 1) / 2 > u) --bj;
  const int bi = u - bj * (bj + 1) / 2;
  const bool diag = (bi == bj);
  const bool posb = (bj == bi + BATCH / 128);
  const int tileRow = bi * 128;
  const int tileCol = bj * 128;

  __shared__ __align__(16) ushort shA[3 * 4096];
  __shared__ __align__(16) ushort shB[3 * 4096];
  __shared__ float redR[2][128];
  __shared__ float redC[2][128];

  const int t    = threadIdx.x;
  const int w    = t >> 6;
  const int l    = t & 63;
  const int quad = l >> 4;
  const int lo   = l & 15;
  const int wm   = w >> 1;
  const int wn   = w & 1;

  // staging: lane l of wave w stages chunks c0 = w*128+l, c1 = c0+64 into
  // LDS at chunk*16B (wave-uniform base + lane*16). k-chunk XOR-swizzled.
  const int c0 = w * 128 + l;
  const int c1 = c0 + 64;
  const int r0 = c0 >> 2, k0 = ((c0 & 3) ^ ((r0 >> 1) & 3)) * 8;
  const int r1 = c1 >> 2, k1 = ((c1 & 3) ^ ((r1 >> 1) & 3)) * 8;
  const ushort* gA0 = zn + (size_t)(tileRow + r0) * DIM + k0;
  const ushort* gA1 = zn + (size_t)(tileRow + r1) * DIM + k1;
  const ushort* gB0 = zn + (size_t)(tileCol + r0) * DIM + k0;
  const ushort* gB1 = zn + (size_t)(tileCol + r1) * DIM + k1;
  ushort* lA0 = shA + w * 1024;
  ushort* lA1 = shA + w * 1024 + 512;
  ushort* lB0 = shB + w * 1024;
  ushort* lB1 = shB + w * 1024 + 512;

  floatx4 acc[4][4];
  #pragma unroll
  for (int i = 0; i < 4; ++i)
    #pragma unroll
    for (int j = 0; j < 4; ++j)
      acc[i][j] = (floatx4){0.f, 0.f, 0.f, 0.f};

  // fragment read offsets (ushorts): chunk = R*4 + (quad ^ ((lo>>1)&3))
  const int sw2  = (quad ^ ((lo >> 1) & 3)) * 8;
  const int aOff = (wm * 64 + lo) * 32 + sw2;  // + i*512
  const int bOff = (wn * 64 + lo) * 32 + sw2;  // + j*512

  // prologue: stage K-tiles 0,1 into ring slots 0,1
  ASYNC16(gA0, lA0);       ASYNC16(gA1, lA1);
  ASYNC16(gB0, lB0);       ASYNC16(gB1, lB1);
  ASYNC16(gA0 + 32, lA0 + 4096); ASYNC16(gA1 + 32, lA1 + 4096);
  ASYNC16(gB0 + 32, lB0 + 4096); ASYNC16(gB1 + 32, lB1 + 4096);

  #pragma unroll
  for (int it = 0; it < 16; ++it) {
    if (it < 15) { SWAIT4(); } else { SWAIT0(); }   // stage-it loads done
    SBAR();
    if (it + 2 < 16) {                              // prefetch stage it+2
      const int no = ((it + 2) % 3) * 4096;
      const int gk = (it + 2) * 32;
      ASYNC16(gA0 + gk, lA0 + no); ASYNC16(gA1 + gk, lA1 + no);
      ASYNC16(gB0 + gk, lB0 + no); ASYNC16(gB1 + gk, lB1 + no);
    }
    const int co = (it % 3) * 4096;
    bf16x8 aF[4], bF[4];
    #pragma unroll
    for (int i = 0; i < 4; ++i) aF[i] = *(const bf16x8*)(shA + co + aOff + i * 512);
    #pragma unroll
    for (int j = 0; j < 4; ++j) bF[j] = *(const bf16x8*)(shB + co + bOff + j * 512);
    #pragma unroll
    for (int i = 0; i < 4; ++i)
      #pragma unroll
      for (int j = 0; j < 4; ++j)
        acc[i][j] = __builtin_amdgcn_mfma_f32_16x16x32_bf16(aF[i], bF[j],
                                                            acc[i][j], 0, 0, 0);
  }

  // ---- epilogue. C/D layout: col = lo, row = quad*4 + r (within 16x16)
  float rs[4][4];
  float cs[4];
  #pragma unroll
  for (int i = 0; i < 4; ++i)
    #pragma unroll
    for (int r = 0; r < 4; ++r) rs[i][r] = 0.f;
  #pragma unroll
  for (int j = 0; j < 4; ++j) cs[j] = 0.f;

  #pragma unroll
  for (int i = 0; i < 4; ++i)
    #pragma unroll
    for (int j = 0; j < 4; ++j)
      #pragma unroll
      for (int r = 0; r < 4; ++r) {
        const float e = __expf(acc[i][j][r] * 10.0f - 10.0f);
        rs[i][r] += e;
        cs[j] += e;
      }

  // block-local diagonal lanes: wm==wn, lo == quad*4 + r (quad == lo>>2)
  if (wm == wn && quad == (lo >> 2)) {
    const int r = lo & 3;
    if (diag) {  // remove self-similarity from row & col sums
      #pragma unroll
      for (int i = 0; i < 4; ++i) {
        const float e = __expf(acc[i][i][r] * 10.0f - 10.0f);
        rs[i][r] -= e;
        cs[i] -= e;
      }
    }
    if (posb) {  // positives: col == row + BATCH
      #pragma unroll
      for (int i = 0; i < 4; ++i) {
        const int row = tileRow + wm * 64 + i * 16 + lo;
        const float v = acc[i][i][r] * 10.0f;
        P[row] = v;
        P[row + BATCH] = v;
      }
    }
  }

  // row sums: reduce across 16 column-lanes (low 4 lane bits)
  #pragma unroll
  for (int m = 1; m < 16; m <<= 1) {
    #pragma unroll
    for (int i = 0; i < 4; ++i)
      #pragma unroll
      for (int r = 0; r < 4; ++r)
        rs[i][r] += __shfl_xor(rs[i][r], m, 64);
  }
  if (lo == 0) {
    #pragma unroll
    for (int i = 0; i < 4; ++i)
      #pragma unroll
      for (int r = 0; r < 4; ++r)
        redR[wn][wm * 64 + i * 16 + quad * 4 + r] = rs[i][r];
  }
  // col sums: reduce across the 4 quads (lane bits 4,5)
  #pragma unroll
  for (int m = 16; m < 64; m <<= 1) {
    #pragma unroll
    for (int j = 0; j < 4; ++j) cs[j] += __shfl_xor(cs[j], m, 64);
  }
  if (quad == 0) {
    #pragma unroll
    for (int j = 0; j < 4; ++j)
      redC[wm][wn * 64 + j * 16 + lo] = cs[j];
  }
  __syncthreads();
  if (t < 128) {
    atomicAdd(&S[tileRow + t], redR[0][t] + redR[1][t]);
  } else if (!diag) {
    const int c = t - 128;
    atomicAdd(&S[tileCol + c], redC[0][c] + redC[1][c]);
  }

  // ---- last-block loss reduction
  __threadfence();                       // release S/P updates (device scope)
  __shared__ unsigned ticket;
  if (t == 0) ticket = atomicAdd(done, 1u);
  __syncthreads();
  if (ticket == NTILE - 1) {
    __threadfence();                     // acquire all other blocks' S/P
    float acc2 = 0.f;
    for (int i = t; i < NTOT; i += 256)
      acc2 += 10.0f + logf(S[i]) - P[i];
    #pragma unroll
    for (int m = 1; m < 64; m <<= 1) acc2 += __shfl_xor(acc2, m, 64);
    __shared__ float sb[4];
    if (l == 0) sb[w] = acc2;
    __syncthreads();
    if (t == 0)
      out[0] = (sb[0] + sb[1] + sb[2] + sb[3]) * (1.0f / (float)NTOT);
  }
}

extern "C" void kernel_launch(void* const* d_in, const int* in_sizes, int n_in,
                              void* d_out, int out_size, void* d_ws, size_t ws_size,
                              hipStream_t stream) {
  const float* zi = (const float*)d_in[0];
  const float* zj = (const float*)d_in[1];
  ushort*   zn   = (ushort*)d_ws;                                  // 8 MB bf16
  float*    S    = (float*)((char*)d_ws + (size_t)NTOT * DIM * 2); // 32 KB
  float*    P    = S + NTOT;                                       // 32 KB
  unsigned* done = (unsigned*)(P + NTOT);                          // 4 B
  float*    out  = (float*)d_out;

  nrm_kernel<<<NTOT / 4, 256, 0, stream>>>(zi, zj, zn, S, done);
  simsum_kernel<<<NTILE, 256, 0, stream>>>(zn, S, P, done, out);
}